// Round 10
// baseline (510.074 us; speedup 1.0000x reference)
//
#include <hip/hip_runtime.h>
#include <stdint.h>

// ---------------------------------------------------------------------------
// gcnmask, factored form (verified passing r2/r4, absmax 0.0625):
//   A = x @ w_mask[:128], B = x @ w_mask[128:]
//   x_new[n] = x[n] + sum_e keep(e,f)*sigmoid(A[n]+B[dst_e])*2.5*x[dst_e]
//   out = segment_sum(adj * (x_new @ w0)[dst], src)
// Dropout: threefry2x32 partitionable, keep <=> (o0^o1) < 1717987328u (bit-exact).
// r4 evidence: edge_agg VGPR=24 -> no load pipelining, real VALU issue ~50%.
// r5: explicit SW pipeline + scalar (SMEM) addressing + float2 BX interleave.
// ---------------------------------------------------------------------------

#define NNODES 50000
#define FDIM 128

__device__ __forceinline__ uint32_t rotl32(uint32_t x, int r) {
  return (x << r) | (x >> (32 - r));  // v_alignbit_b32
}

__device__ __forceinline__ void threefry2x32(uint32_t k0, uint32_t k1,
                                             uint32_t x0, uint32_t x1,
                                             uint32_t& o0, uint32_t& o1) {
  uint32_t k2 = k0 ^ k1 ^ 0x1BD11BDAu;
  x0 += k0; x1 += k1;
  x0 += x1; x1 = rotl32(x1, 13); x1 ^= x0;
  x0 += x1; x1 = rotl32(x1, 15); x1 ^= x0;
  x0 += x1; x1 = rotl32(x1, 26); x1 ^= x0;
  x0 += x1; x1 = rotl32(x1,  6); x1 ^= x0;
  x0 += k1; x1 += k2 + 1u;
  x0 += x1; x1 = rotl32(x1, 17); x1 ^= x0;
  x0 += x1; x1 = rotl32(x1, 29); x1 ^= x0;
  x0 += x1; x1 = rotl32(x1, 16); x1 ^= x0;
  x0 += x1; x1 = rotl32(x1, 24); x1 ^= x0;
  x0 += k2; x1 += k0 + 2u;
  x0 += x1; x1 = rotl32(x1, 13); x1 ^= x0;
  x0 += x1; x1 = rotl32(x1, 15); x1 ^= x0;
  x0 += x1; x1 = rotl32(x1, 26); x1 ^= x0;
  x0 += x1; x1 = rotl32(x1,  6); x1 ^= x0;
  x0 += k0; x1 += k1 + 3u;
  x0 += x1; x1 = rotl32(x1, 17); x1 ^= x0;
  x0 += x1; x1 = rotl32(x1, 29); x1 ^= x0;
  x0 += x1; x1 = rotl32(x1, 16); x1 ^= x0;
  x0 += x1; x1 = rotl32(x1, 24); x1 ^= x0;
  x0 += k1; x1 += k2 + 4u;
  x0 += x1; x1 = rotl32(x1, 13); x1 ^= x0;
  x0 += x1; x1 = rotl32(x1, 15); x1 ^= x0;
  x0 += x1; x1 = rotl32(x1, 26); x1 ^= x0;
  x0 += x1; x1 = rotl32(x1,  6); x1 ^= x0;
  x0 += k2; x1 += k0 + 5u;
  o0 = x0; o1 = x1;
}

__device__ __forceinline__ bool keep_drop(uint32_t idx) {
  uint32_t o0, o1;
  threefry2x32(0u, 42u, 0u, idx, o0, o1);
  return (o0 ^ o1) < 1717987328u;  // == u < f32(0.4), bit-exact
}

__device__ __forceinline__ float sigmoid_f(float z) {
  float e = __builtin_amdgcn_exp2f(z * -1.44269504088896340736f);
  return __builtin_amdgcn_rcpf(1.0f + e);
}

__device__ __forceinline__ int rfl(int v) { return __builtin_amdgcn_readfirstlane(v); }

__device__ __forceinline__ bool detect_i64(const int* p, int n) {
  int i = (n / 2) | 1;
  return p[i] == 0 && p[i + 2] == 0 && p[i + 4] == 0;
}

__device__ __forceinline__ int idx_at(const void* p, int i, bool is64) {
  return is64 ? (int)((const long long*)p)[i] : ((const int*)p)[i];
}

__device__ __forceinline__ int lower_bound_idx(const void* a, int n, bool is64, int v) {
  int lo = 0, hi = n;
  while (lo < hi) {
    int mid = (lo + hi) >> 1;
    if (idx_at(a, mid, is64) < v) lo = mid + 1; else hi = mid;
  }
  return lo;
}

__global__ __launch_bounds__(256) void rowptr_kernel(const void* __restrict__ src, int nE,
                                                     int* __restrict__ rowptr) {
  bool is64 = detect_i64((const int*)src, nE);
  int n = blockIdx.x * blockDim.x + threadIdx.x;
  if (n <= NNODES) rowptr[n] = lower_bound_idx(src, nE, is64, n);
}

__global__ __launch_bounds__(256) void cvt_dst(const void* __restrict__ dst, int nE,
                                               int* __restrict__ dst32) {
  bool is64 = detect_i64((const int*)dst, nE);
  int i = blockIdx.x * blockDim.x + threadIdx.x;
  if (i < nE) {
    int d = idx_at(dst, i, is64);
    dst32[i] = min(max(d, 0), NNODES - 1);
  }
}

// Fused A,B = x @ Wtop, x @ Wbot. When USE_BX, emit interleaved (B,x) float2 rows.
#define MMR 16
template <bool USE_BX>
__global__ __launch_bounds__(128) void matmulAB_k(const float* __restrict__ in,
                                                  const float* __restrict__ W,
                                                  float* __restrict__ A,
                                                  float* __restrict__ Bout, int nrows) {
  __shared__ float xs[MMR][FDIM];
  int r0 = blockIdx.x * MMR;
  int t = threadIdx.x;
  #pragma unroll
  for (int r = 0; r < MMR; ++r) {
    int row = r0 + r;
    xs[r][t] = (row < nrows) ? in[row * FDIM + t] : 0.0f;
  }
  __syncthreads();
  float accA[MMR] = {}, accB[MMR] = {};
  for (int k = 0; k < FDIM; k += 4) {
    float wa0 = W[(k + 0) * FDIM + t], wa1 = W[(k + 1) * FDIM + t];
    float wa2 = W[(k + 2) * FDIM + t], wa3 = W[(k + 3) * FDIM + t];
    float wb0 = W[(FDIM + k + 0) * FDIM + t], wb1 = W[(FDIM + k + 1) * FDIM + t];
    float wb2 = W[(FDIM + k + 2) * FDIM + t], wb3 = W[(FDIM + k + 3) * FDIM + t];
    #pragma unroll
    for (int r = 0; r < MMR; ++r) {
      float4 xv = *(const float4*)&xs[r][k];
      accA[r] += xv.x * wa0; accA[r] += xv.y * wa1;
      accA[r] += xv.z * wa2; accA[r] += xv.w * wa3;
      accB[r] += xv.x * wb0; accB[r] += xv.y * wb1;
      accB[r] += xv.z * wb2; accB[r] += xv.w * wb3;
    }
  }
  #pragma unroll
  for (int r = 0; r < MMR; ++r) {
    int row = r0 + r;
    if (row < nrows) {
      A[row * FDIM + t] = accA[r];
      if (USE_BX) ((float2*)Bout)[(row << 7) + t] = make_float2(accB[r], xs[r][t]);
      else        Bout[row * FDIM + t] = accB[r];
    }
  }
}

// out[N,128] = in @ W, 16-row register blocking
__global__ __launch_bounds__(128) void matmul16(const float* __restrict__ in,
                                                const float* __restrict__ W,
                                                float* __restrict__ out, int nrows) {
  __shared__ float xs[MMR][FDIM];
  int r0 = blockIdx.x * MMR;
  int t = threadIdx.x;
  #pragma unroll
  for (int r = 0; r < MMR; ++r) {
    int row = r0 + r;
    xs[r][t] = (row < nrows) ? in[row * FDIM + t] : 0.0f;
  }
  __syncthreads();
  float acc[MMR] = {};
  for (int k = 0; k < FDIM; k += 4) {
    float w0 = W[(k + 0) * FDIM + t], w1 = W[(k + 1) * FDIM + t];
    float w2 = W[(k + 2) * FDIM + t], w3 = W[(k + 3) * FDIM + t];
    #pragma unroll
    for (int r = 0; r < MMR; ++r) {
      float4 xv = *(const float4*)&xs[r][k];
      acc[r] += xv.x * w0; acc[r] += xv.y * w1;
      acc[r] += xv.z * w2; acc[r] += xv.w * w3;
    }
  }
  #pragma unroll
  for (int r = 0; r < MMR; ++r) {
    int row = r0 + r;
    if (row < nrows) out[row * FDIM + t] = acc[r];
  }
}

// Software-pipelined edge aggregation: prefetch quad k+1's gathers, then the
// ~600cy of threefry VALU for quad k hides their latency. Scalar (uniform)
// dst/rowptr indices -> SMEM loads + SGPR gather bases.
template <bool USE_BX>
__global__ __launch_bounds__(128, 4) void edge_agg_k(const float* __restrict__ x,
                                                     const float* __restrict__ BorBX,
                                                     const int* __restrict__ dst32,
                                                     const int* __restrict__ rowptr,
                                                     const float* __restrict__ A,
                                                     float* __restrict__ x_new) {
  int n = blockIdx.x;
  int f = threadIdx.x;
  int lo = rfl(rowptr[n]);
  int hi = rfl(rowptr[n + 1]);
  const float2* BX2 = (const float2*)BorBX;
  const float*  Bf  = BorBX + f;
  const float*  xf  = x + f;
  float a = A[(n << 7) + f];
  float acc0 = 0.f, acc1 = 0.f, acc2 = 0.f, acc3 = 0.f;
  int e = lo;
  if (hi - lo >= 4) {
    float2 v0, v1, v2, v3;  // (B[d][f], x[d][f]) pairs for current quad
    {
      int d0 = rfl(dst32[e]), d1 = rfl(dst32[e + 1]);
      int d2 = rfl(dst32[e + 2]), d3 = rfl(dst32[e + 3]);
      if (USE_BX) {
        v0 = BX2[(d0 << 7) + f]; v1 = BX2[(d1 << 7) + f];
        v2 = BX2[(d2 << 7) + f]; v3 = BX2[(d3 << 7) + f];
      } else {
        v0 = make_float2(Bf[d0 << 7], xf[d0 << 7]);
        v1 = make_float2(Bf[d1 << 7], xf[d1 << 7]);
        v2 = make_float2(Bf[d2 << 7], xf[d2 << 7]);
        v3 = make_float2(Bf[d3 << 7], xf[d3 << 7]);
      }
    }
    for (; e + 4 <= hi;) {
      int ne = (e + 8 <= hi) ? e + 4 : e;  // next quad (self-reload on last iter)
      int nd0 = rfl(dst32[ne]), nd1 = rfl(dst32[ne + 1]);
      int nd2 = rfl(dst32[ne + 2]), nd3 = rfl(dst32[ne + 3]);
      float2 w0, w1, w2, w3;
      if (USE_BX) {
        w0 = BX2[(nd0 << 7) + f]; w1 = BX2[(nd1 << 7) + f];
        w2 = BX2[(nd2 << 7) + f]; w3 = BX2[(nd3 << 7) + f];
      } else {
        w0 = make_float2(Bf[nd0 << 7], xf[nd0 << 7]);
        w1 = make_float2(Bf[nd1 << 7], xf[nd1 << 7]);
        w2 = make_float2(Bf[nd2 << 7], xf[nd2 << 7]);
        w3 = make_float2(Bf[nd3 << 7], xf[nd3 << 7]);
      }
      // long VALU section (covers the prefetch latency)
      uint32_t idx = ((uint32_t)e << 7) + (uint32_t)f;
      bool k0 = keep_drop(idx);
      bool k1 = keep_drop(idx + 128u);
      bool k2 = keep_drop(idx + 256u);
      bool k3 = keep_drop(idx + 384u);
      float m0 = sigmoid_f(a + v0.x), m1 = sigmoid_f(a + v1.x);
      float m2 = sigmoid_f(a + v2.x), m3 = sigmoid_f(a + v3.x);
      acc0 += k0 ? (m0 * 2.5f) * v0.y : 0.0f;
      acc1 += k1 ? (m1 * 2.5f) * v1.y : 0.0f;
      acc2 += k2 ? (m2 * 2.5f) * v2.y : 0.0f;
      acc3 += k3 ? (m3 * 2.5f) * v3.y : 0.0f;
      v0 = w0; v1 = w1; v2 = w2; v3 = w3;
      e += 4;
    }
  }
  for (; e < hi; ++e) {
    int d = rfl(dst32[e]);
    uint32_t idx = ((uint32_t)e << 7) + (uint32_t)f;
    float bb, xx;
    if (USE_BX) { float2 v = BX2[(d << 7) + f]; bb = v.x; xx = v.y; }
    else        { bb = Bf[d << 7]; xx = xf[d << 7]; }
    float m = sigmoid_f(a + bb);
    if (keep_drop(idx)) acc0 += (m * 2.5f) * xx;
  }
  x_new[(n << 7) + f] = x[(n << 7) + f] + ((acc0 + acc1) + (acc2 + acc3));
}

// out[n] = sum_e adj[e]*support[dst_e]; 8-wide pipelined gather, scalar adj/dst.
__global__ __launch_bounds__(128, 4) void edge_out(const float* __restrict__ support,
                                                   const int* __restrict__ dst32,
                                                   const int* __restrict__ rowptr,
                                                   const float* __restrict__ adj,
                                                   float* __restrict__ out) {
  int n = blockIdx.x;
  int f = threadIdx.x;
  int lo = rfl(rowptr[n]), hi = rfl(rowptr[n + 1]);
  const float* Sf = support + f;
  float a0 = 0.f, a1 = 0.f, a2 = 0.f, a3 = 0.f;
  int e = lo;
  if (hi - lo >= 8) {
    float s0, s1, s2, s3, s4, s5, s6, s7;
    float w0, w1, w2, w3, w4, w5, w6, w7;
    {
      int d0 = rfl(dst32[e]),     d1 = rfl(dst32[e + 1]);
      int d2 = rfl(dst32[e + 2]), d3 = rfl(dst32[e + 3]);
      int d4 = rfl(dst32[e + 4]), d5 = rfl(dst32[e + 5]);
      int d6 = rfl(dst32[e + 6]), d7 = rfl(dst32[e + 7]);
      s0 = Sf[d0 << 7]; s1 = Sf[d1 << 7]; s2 = Sf[d2 << 7]; s3 = Sf[d3 << 7];
      s4 = Sf[d4 << 7]; s5 = Sf[d5 << 7]; s6 = Sf[d6 << 7]; s7 = Sf[d7 << 7];
      w0 = adj[e]; w1 = adj[e + 1]; w2 = adj[e + 2]; w3 = adj[e + 3];
      w4 = adj[e + 4]; w5 = adj[e + 5]; w6 = adj[e + 6]; w7 = adj[e + 7];
    }
    for (; e + 8 <= hi;) {
      int ne = (e + 16 <= hi) ? e + 8 : e;
      int nd0 = rfl(dst32[ne]),     nd1 = rfl(dst32[ne + 1]);
      int nd2 = rfl(dst32[ne + 2]), nd3 = rfl(dst32[ne + 3]);
      int nd4 = rfl(dst32[ne + 4]), nd5 = rfl(dst32[ne + 5]);
      int nd6 = rfl(dst32[ne + 6]), nd7 = rfl(dst32[ne + 7]);
      float t0 = Sf[nd0 << 7], t1 = Sf[nd1 << 7], t2 = Sf[nd2 << 7], t3 = Sf[nd3 << 7];
      float t4 = Sf[nd4 << 7], t5 = Sf[nd5 << 7], t6 = Sf[nd6 << 7], t7 = Sf[nd7 << 7];
      float u0 = adj[ne], u1 = adj[ne + 1], u2 = adj[ne + 2], u3 = adj[ne + 3];
      float u4 = adj[ne + 4], u5 = adj[ne + 5], u6 = adj[ne + 6], u7 = adj[ne + 7];
      a0 += w0 * s0; a1 += w1 * s1; a2 += w2 * s2; a3 += w3 * s3;
      a0 += w4 * s4; a1 += w5 * s5; a2 += w6 * s6; a3 += w7 * s7;
      s0 = t0; s1 = t1; s2 = t2; s3 = t3; s4 = t4; s5 = t5; s6 = t6; s7 = t7;
      w0 = u0; w1 = u1; w2 = u2; w3 = u3; w4 = u4; w5 = u5; w6 = u6; w7 = u7;
      e += 8;
    }
  }
  for (; e < hi; ++e) a0 += adj[e] * Sf[rfl(dst32[e]) << 7];
  out[(n << 7) + f] = (a0 + a1) + (a2 + a3);
}

extern "C" void kernel_launch(void* const* d_in, const int* in_sizes, int n_in,
                              void* d_out, int out_size, void* d_ws, size_t ws_size,
                              hipStream_t stream) {
  const float* x      = (const float*)d_in[0];
  const void*  src    = d_in[1];
  const void*  dst    = d_in[2];
  const float* adj    = (const float*)d_in[3];
  const float* w_mask = (const float*)d_in[4];
  const float* w0     = (const float*)d_in[5];
  float* out = (float*)d_out;

  int nE = in_sizes[1];
  const size_t NF = (size_t)NNODES * FDIM;

  // BX layout needs A(NF) + BX(2NF) + x_new(NF) + rowptr + dst32 ≈ 106 MB.
  // Fallback (validated r4 at ~80 MB): A + B + x_new + rowptr + dst32.
  size_t need_bx = (4 * NF + (size_t)(NNODES + 1) + (size_t)nE) * 4;
  bool use_bx = ws_size >= need_bx;

  float* A      = (float*)d_ws;
  float* Bbuf   = A + NF;                       // B (NF) or BX (2*NF)
  float* x_new  = Bbuf + (use_bx ? 2 * NF : NF);
  int*   rowptr = (int*)(x_new + NF);
  int*   dst32  = rowptr + (NNODES + 1);
  float* support = A;  // A dead after edge_agg

  rowptr_kernel<<<(NNODES + 256) / 256, 256, 0, stream>>>(src, nE, rowptr);
  cvt_dst<<<(nE + 255) / 256, 256, 0, stream>>>(dst, nE, dst32);
  if (use_bx) {
    matmulAB_k<true><<<(NNODES + MMR - 1) / MMR, 128, 0, stream>>>(x, w_mask, A, Bbuf, NNODES);
    edge_agg_k<true><<<NNODES, 128, 0, stream>>>(x, Bbuf, dst32, rowptr, A, x_new);
  } else {
    matmulAB_k<false><<<(NNODES + MMR - 1) / MMR, 128, 0, stream>>>(x, w_mask, A, Bbuf, NNODES);
    edge_agg_k<false><<<NNODES, 128, 0, stream>>>(x, Bbuf, dst32, rowptr, A, x_new);
  }
  matmul16<<<(NNODES + MMR - 1) / MMR, 128, 0, stream>>>(x_new, w0, support, NNODES);
  edge_out<<<NNODES, 128, 0, stream>>>(support, dst32, rowptr, adj, out);
}